// Round 1
// baseline (805.356 us; speedup 1.0000x reference)
//
#include <hip/hip_runtime.h>
#include <math.h>

#define NB 256
#define NL 50
#define NK 100
#define NHID 64

// ---- tiny pre-pass: W1T[m][j] = W1[j][m]  (48x96) into workspace ----
__global__ __launch_bounds__(256) void w1t_kernel(const float* __restrict__ W1,
                                                  float* __restrict__ W1T) {
    int idx = threadIdx.x + blockIdx.x * 256;
    if (idx < 96 * 48) {
        int m = idx / 96, j = idx % 96;
        W1T[idx] = W1[j * 48 + m];
    }
}

// ---- main fused kernel: one block per (b,l) ----
__global__ __launch_bounds__(128) void edge_kernel(
    const int* __restrict__ history,
    const float* __restrict__ neighbor,
    const float* __restrict__ item_table,
    const float* __restrict__ Wa, const float* __restrict__ ba,
    const float* __restrict__ b1v,
    const float* __restrict__ W1T,
    const float* __restrict__ W2, const float* __restrict__ b2,
    const float* __restrict__ W3, const float* __restrict__ b3,
    const float* __restrict__ Wh, const float* __restrict__ bh,
    float* __restrict__ acc_out)   // [NB][64] fp32, pre-zeroed
{
    const int bl  = blockIdx.x;
    const int b   = bl / NL;
    const int tid = threadIdx.x;

    __shared__ float nb_s[NK * 65];   // padded stride 65: conflict-free both axes
    __shared__ float hist_s[64];
    __shared__ float base1_s[96];
    __shared__ float red_s[128];
    __shared__ float agg_s[64];

    const int hid = history[bl];
    if (tid < 64) hist_s[tid] = item_table[(size_t)hid * NHID + tid];

    // stage neighbor tile [100][64] -> LDS (coalesced global reads)
    const float* nbg = neighbor + (size_t)bl * (NK * NHID);
    for (int f = tid; f < NK * NHID; f += 128)
        nb_s[(f >> 6) * 65 + (f & 63)] = nbg[f];
    __syncthreads();

    // base1[j] = ba[j] + sum_i hist[i] * Wa[i][j]   (hist part shared by all K edges)
    if (tid < 96) {
        float a = ba[tid];
        #pragma unroll 4
        for (int i = 0; i < 64; ++i)
            a += hist_s[i] * Wa[i * 96 + tid];
        base1_s[tid] = a;
    }
    __syncthreads();

    const bool valid = tid < NK;
    const int  e     = valid ? tid : NK - 1;
    const float* nbrow = &nb_s[e * 65];

    // ---- layer 1: z1[96] = relu(base1 + nb . Wa_bot) ----
    float z1[96];
    #pragma unroll
    for (int j = 0; j < 96; ++j) z1[j] = base1_s[j];
    for (int i = 0; i < 64; ++i) {
        float v = nbrow[i];
        const float* wr = &Wa[(64 + i) * 96];   // uniform address -> s_load
        #pragma unroll
        for (int j = 0; j < 96; ++j) z1[j] += v * wr[j];
    }
    #pragma unroll
    for (int j = 0; j < 96; ++j) z1[j] = fmaxf(z1[j], 0.f);

    // ---- layers 2+3 fused: per m, dot(z1, W1T[m]) -> relu -> feed z3 ----
    float z3[16];
    #pragma unroll
    for (int m2 = 0; m2 < 16; ++m2) z3[m2] = b2[m2];
    for (int m = 0; m < 48; ++m) {
        const float* wr = &W1T[m * 96];        // contiguous uniform row
        float a0 = 0.f, a1 = 0.f, a2 = 0.f, a3 = 0.f;
        #pragma unroll
        for (int j = 0; j < 96; j += 4) {
            a0 += z1[j]     * wr[j];
            a1 += z1[j + 1] * wr[j + 1];
            a2 += z1[j + 2] * wr[j + 2];
            a3 += z1[j + 3] * wr[j + 3];
        }
        float h2m = fmaxf(b1v[m] + ((a0 + a1) + (a2 + a3)), 0.f);
        const float* w2r = &W2[m * 16];
        #pragma unroll
        for (int m2 = 0; m2 < 16; ++m2) z3[m2] += h2m * w2r[m2];
    }
    float lg = b3[0];
    #pragma unroll
    for (int m2 = 0; m2 < 16; ++m2) lg += fmaxf(z3[m2], 0.f) * W3[m2];

    // ---- softmax over the 100 edges ----
    float logit = valid ? lg : -1e30f;
    red_s[tid] = logit;
    __syncthreads();
    for (int s = 64; s > 0; s >>= 1) {
        if (tid < s) red_s[tid] = fmaxf(red_s[tid], red_s[tid + s]);
        __syncthreads();
    }
    float mx = red_s[0];
    __syncthreads();
    float p = valid ? __expf(logit - mx) : 0.f;
    red_s[tid] = p;
    __syncthreads();
    for (int s = 64; s > 0; s >>= 1) {
        if (tid < s) red_s[tid] += red_s[tid + s];
        __syncthreads();
    }
    float inv_sum = 1.f / red_s[0];
    __syncthreads();
    red_s[tid] = p * inv_sum;     // red_s now holds softmax weights
    __syncthreads();

    // ---- agg[h] = sum_k w[k] * nb[k][h]  (exact fp32 from LDS) ----
    if (tid < 64) {
        float a = 0.f;
        for (int k = 0; k < NK; ++k)
            a += red_s[k] * nb_s[k * 65 + tid];
        agg_s[tid] = a;
    }
    __syncthreads();

    // ---- heads: out64[n*16+d] = bh + sum_h agg[h]*Wh[n][h][d]; accumulate over l ----
    if (tid < 64) {
        const int n = tid >> 4, d = tid & 15;
        float hv = bh[tid];
        #pragma unroll 4
        for (int h = 0; h < 64; ++h)
            hv += agg_s[h] * Wh[n * (64 * 16) + h * 16 + d];
        atomicAdd(&acc_out[b * NHID + tid], hv);
    }
}

// ---- final head: combined = [user_emb | agg_mean] -> relu(Wf1) -> sigmoid(Wo) ----
__global__ __launch_bounds__(64) void final_kernel(
    const int* __restrict__ user_ids,
    const float* __restrict__ user_table,
    const float* __restrict__ acc,
    const float* __restrict__ Wf1, const float* __restrict__ bf1,
    const float* __restrict__ Wo,  const float* __restrict__ bo,
    float* __restrict__ out)
{
    const int b = blockIdx.x, h = threadIdx.x;
    __shared__ float ue[64], ag[64];
    const int uid = user_ids[b];
    ue[h] = user_table[(size_t)uid * 64 + h];
    ag[h] = acc[b * 64 + h] * (1.f / 50.f);
    __syncthreads();
    float z = bf1[h];
    #pragma unroll 4
    for (int i = 0; i < 64; ++i) z += ue[i] * Wf1[i * 64 + h];
    #pragma unroll 4
    for (int i = 0; i < 64; ++i) z += ag[i] * Wf1[(64 + i) * 64 + h];
    float t = fmaxf(z, 0.f) * Wo[h];
    #pragma unroll
    for (int off = 32; off > 0; off >>= 1) t += __shfl_down(t, off, 64);
    if (h == 0) out[b] = 1.f / (1.f + __expf(-(t + bo[0])));
}

extern "C" void kernel_launch(void* const* d_in, const int* in_sizes, int n_in,
                              void* d_out, int out_size, void* d_ws, size_t ws_size,
                              hipStream_t stream) {
    const int*   user_ids   = (const int*)d_in[0];
    const int*   history    = (const int*)d_in[2];
    const float* neighbor   = (const float*)d_in[3];
    const float* user_table = (const float*)d_in[4];
    const float* item_table = (const float*)d_in[5];
    const float* Wa  = (const float*)d_in[6];
    const float* ba  = (const float*)d_in[7];
    const float* W1  = (const float*)d_in[8];
    const float* b1  = (const float*)d_in[9];
    const float* W2  = (const float*)d_in[10];
    const float* b2  = (const float*)d_in[11];
    const float* W3  = (const float*)d_in[12];
    const float* b3  = (const float*)d_in[13];
    const float* Wh  = (const float*)d_in[14];
    const float* bh  = (const float*)d_in[15];
    const float* Wf1 = (const float*)d_in[16];
    const float* bf1 = (const float*)d_in[17];
    const float* Wo  = (const float*)d_in[18];
    const float* bo  = (const float*)d_in[19];

    float* acc = (float*)d_ws;                    // NB*64 floats, zeroed each call
    float* W1T = (float*)d_ws + NB * NHID;        // 48*96 floats

    hipMemsetAsync(acc, 0, NB * NHID * sizeof(float), stream);
    w1t_kernel<<<(96 * 48 + 255) / 256, 256, 0, stream>>>(W1, W1T);
    edge_kernel<<<NB * NL, 128, 0, stream>>>(history, neighbor, item_table,
        Wa, ba, b1, W1T, W2, b2, W3, b3, Wh, bh, acc);
    final_kernel<<<NB, 64, 0, stream>>>(user_ids, user_table, acc, Wf1, bf1, Wo, bo,
                                        (float*)d_out);
}

// Round 5
// 641.777 us; speedup vs baseline: 1.2549x; 1.2549x over previous
//
#include <hip/hip_runtime.h>
#include <math.h>

#define NB 256
#define NL 50
#define NK 100
#define NHID 64

// ---- main fused kernel: one block per (b,l) ----
__global__ __launch_bounds__(128) void edge_kernel(
    const int* __restrict__ history,
    const float* __restrict__ neighbor,
    const float* __restrict__ item_table,
    const float* __restrict__ Wa, const float* __restrict__ ba,
    const float* __restrict__ W1, const float* __restrict__ b1v,
    const float* __restrict__ W2, const float* __restrict__ b2,
    const float* __restrict__ W3, const float* __restrict__ b3,
    const float* __restrict__ Wh, const float* __restrict__ bh,
    float* __restrict__ acc_out)   // [NB][64] fp32, pre-zeroed
{
    const int bl  = blockIdx.x;
    const int b   = bl / NL;
    const int tid = threadIdx.x;

    __shared__ float nb_s[NK * 65];   // padded stride 65: conflict-free both axes
    __shared__ float hist_s[64];
    __shared__ float base1_s[96];
    __shared__ float red_s[128];
    __shared__ float agg_s[64];

    const int hid = history[bl];
    if (tid < 64) hist_s[tid] = item_table[(size_t)hid * NHID + tid];

    // stage neighbor tile [100][64] -> LDS (coalesced global reads)
    const float* nbg = neighbor + (size_t)bl * (NK * NHID);
    for (int f = tid; f < NK * NHID; f += 128)
        nb_s[(f >> 6) * 65 + (f & 63)] = nbg[f];
    __syncthreads();

    // base1[j] = ba[j] + sum_i hist[i] * Wa[i][j]   (hist part shared by all K edges)
    if (tid < 96) {
        float a = ba[tid];
        #pragma unroll 4
        for (int i = 0; i < 64; ++i)
            a += hist_s[i] * Wa[i * 96 + tid];
        base1_s[tid] = a;
    }
    __syncthreads();

    const bool valid = tid < NK;
    const int  e     = valid ? tid : NK - 1;
    const float* nbrow = &nb_s[e * 65];

    // ---- layers 1+2 fused, chunked to avoid register spill ----
    // z2[m] = b1[m] + sum_j relu(z1[j]) * W1[j][m], z1 produced 32 cols at a time
    float z2[48];
    #pragma unroll
    for (int m = 0; m < 48; ++m) z2[m] = b1v[m];

    #pragma unroll
    for (int c = 0; c < 3; ++c) {
        float z1c[32];
        #pragma unroll
        for (int j = 0; j < 32; ++j) z1c[j] = base1_s[c * 32 + j];
        #pragma unroll 2
        for (int i = 0; i < 64; ++i) {
            float v = nbrow[i];
            const float* wr = &Wa[(64 + i) * 96 + c * 32];  // uniform -> s_load
            #pragma unroll
            for (int j = 0; j < 32; ++j) z1c[j] += v * wr[j];
        }
        for (int j = 0; j < 32; ++j) {
            float z = fmaxf(z1c[j], 0.f);
            const float* w1r = &W1[(c * 32 + j) * 48];      // uniform, contiguous
            #pragma unroll
            for (int m = 0; m < 48; ++m) z2[m] += z * w1r[m];
        }
    }

    // ---- layer 3 + logit ----
    float z3[16];
    #pragma unroll
    for (int m2 = 0; m2 < 16; ++m2) z3[m2] = b2[m2];
    for (int m = 0; m < 48; ++m) {
        float h2m = fmaxf(z2[m], 0.f);
        const float* w2r = &W2[m * 16];
        #pragma unroll
        for (int m2 = 0; m2 < 16; ++m2) z3[m2] += h2m * w2r[m2];
    }
    float lg = b3[0];
    #pragma unroll
    for (int m2 = 0; m2 < 16; ++m2) lg += fmaxf(z3[m2], 0.f) * W3[m2];

    // ---- softmax over the 100 edges ----
    float logit = valid ? lg : -1e30f;
    red_s[tid] = logit;
    __syncthreads();
    for (int s = 64; s > 0; s >>= 1) {
        if (tid < s) red_s[tid] = fmaxf(red_s[tid], red_s[tid + s]);
        __syncthreads();
    }
    float mx = red_s[0];
    __syncthreads();
    float p = valid ? __expf(logit - mx) : 0.f;
    red_s[tid] = p;
    __syncthreads();
    for (int s = 64; s > 0; s >>= 1) {
        if (tid < s) red_s[tid] += red_s[tid + s];
        __syncthreads();
    }
    float inv_sum = 1.f / red_s[0];
    __syncthreads();
    red_s[tid] = p * inv_sum;     // red_s now holds softmax weights
    __syncthreads();

    // ---- agg[h] = sum_k w[k] * nb[k][h]  (exact fp32 from LDS) ----
    if (tid < 64) {
        float a = 0.f;
        for (int k = 0; k < NK; ++k)
            a += red_s[k] * nb_s[k * 65 + tid];
        agg_s[tid] = a;
    }
    __syncthreads();

    // ---- heads: out64[n*16+d] = bh + sum_h agg[h]*Wh[n][h][d]; accumulate over l ----
    if (tid < 64) {
        const int n = tid >> 4, d = tid & 15;
        float hv = bh[tid];
        #pragma unroll 4
        for (int h = 0; h < 64; ++h)
            hv += agg_s[h] * Wh[n * (64 * 16) + h * 16 + d];
        atomicAdd(&acc_out[b * NHID + tid], hv);
    }
}

// ---- final head: combined = [user_emb | agg_mean] -> relu(Wf1) -> sigmoid(Wo) ----
__global__ __launch_bounds__(64) void final_kernel(
    const int* __restrict__ user_ids,
    const float* __restrict__ user_table,
    const float* __restrict__ acc,
    const float* __restrict__ Wf1, const float* __restrict__ bf1,
    const float* __restrict__ Wo,  const float* __restrict__ bo,
    float* __restrict__ out)
{
    const int b = blockIdx.x, h = threadIdx.x;
    __shared__ float ue[64], ag[64];
    const int uid = user_ids[b];
    ue[h] = user_table[(size_t)uid * 64 + h];
    ag[h] = acc[b * 64 + h] * (1.f / 50.f);
    __syncthreads();
    float z = bf1[h];
    #pragma unroll 4
    for (int i = 0; i < 64; ++i) z += ue[i] * Wf1[i * 64 + h];
    #pragma unroll 4
    for (int i = 0; i < 64; ++i) z += ag[i] * Wf1[(64 + i) * 64 + h];
    float t = fmaxf(z, 0.f) * Wo[h];
    #pragma unroll
    for (int off = 32; off > 0; off >>= 1) t += __shfl_down(t, off, 64);
    if (h == 0) out[b] = 1.f / (1.f + __expf(-(t + bo[0])));
}

extern "C" void kernel_launch(void* const* d_in, const int* in_sizes, int n_in,
                              void* d_out, int out_size, void* d_ws, size_t ws_size,
                              hipStream_t stream) {
    const int*   user_ids   = (const int*)d_in[0];
    const int*   history    = (const int*)d_in[2];
    const float* neighbor   = (const float*)d_in[3];
    const float* user_table = (const float*)d_in[4];
    const float* item_table = (const float*)d_in[5];
    const float* Wa  = (const float*)d_in[6];
    const float* ba  = (const float*)d_in[7];
    const float* W1  = (const float*)d_in[8];
    const float* b1  = (const float*)d_in[9];
    const float* W2  = (const float*)d_in[10];
    const float* b2  = (const float*)d_in[11];
    const float* W3  = (const float*)d_in[12];
    const float* b3  = (const float*)d_in[13];
    const float* Wh  = (const float*)d_in[14];
    const float* bh  = (const float*)d_in[15];
    const float* Wf1 = (const float*)d_in[16];
    const float* bf1 = (const float*)d_in[17];
    const float* Wo  = (const float*)d_in[18];
    const float* bo  = (const float*)d_in[19];

    float* acc = (float*)d_ws;                    // NB*64 floats, zeroed each call

    hipMemsetAsync(acc, 0, NB * NHID * sizeof(float), stream);
    edge_kernel<<<NB * NL, 128, 0, stream>>>(history, neighbor, item_table,
        Wa, ba, W1, b1, W2, b2, W3, b3, Wh, bh, acc);
    final_kernel<<<NB, 64, 0, stream>>>(user_ids, user_table, acc, Wf1, bf1, Wo, bo,
                                        (float*)d_out);
}